// Round 7
// baseline (103.426 us; speedup 1.0000x reference)
//
#include <hip/hip_runtime.h>
#include <math.h>

// LIF forward scan: v = v*decay*(1-z_prev) + x_t ; z = (v > 0.5)
// B=256, T=1000, H=256. One block (256 thr = 4 waves) per batch row.
// x rows staged into a 3-slot LDS ring via global_load_lds (1KB/instr),
// depth-2 prefetch with PRECISE counted vmcnt (store ops packed 4x via a
// wave-local LDS transpose so newer-op counts fit the 6-bit vmcnt field).
constexpr int T_LEN  = 1000;
constexpr int H_DIM  = 256;
constexpr int BATCH  = 40;               // rows per batch (40 KB)
constexpr int NBATCH = T_LEN / BATCH;    // 25
constexpr int RING   = 3;                // LDS ring slots (120 KB)
constexpr int DEPTH  = 2;                // batches prefetched ahead
constexpr int RPW    = BATCH / 4;        // rows staged per wave = 10

typedef const __attribute__((address_space(1))) float g_f;
typedef __attribute__((address_space(3))) float l_f;
typedef float v4f __attribute__((ext_vector_type(4)));

__global__ __launch_bounds__(256)
void lif_fwd(const float* __restrict__ x,
             const float* __restrict__ decay_logit,
             float* __restrict__ out)
{
#pragma clang fp contract(off)   // must NOT fuse mul+add: match numpy rounding
    __shared__ float X[RING][BATCH][H_DIM];   // 122880 B input ring
    __shared__ float S[4][4][64];             // 4 KB wave-local store-transpose scratch

    const int tid  = threadIdx.x;        // 0..255: chain h = tid
    const int wv   = tid >> 6;           // wave 0..3
    const int lane = tid & 63;
    const int b    = blockIdx.x;         // batch row

    const float* __restrict__ xrow  = x   + (size_t)b * (T_LEN * H_DIM);
    float* __restrict__       obase = out + (size_t)b * (T_LEN * H_DIM);

    // decay = sigmoid(decay_logit[h]); double precision, rounded once to f32.
    const float d = (float)(1.0 / (1.0 + exp(-(double)decay_logit[tid])));
    float v = 0.0f;
    bool  z = false;

    // packed-store lane mapping: lane l stores t-offset (l>>4), cols 4*(l&15)..+3
    const int tsub = lane >> 4;
    const int hofs = (lane & 15) << 2;

    // Stage batch `bt`: wave wv copies rows [wv*RPW, wv*RPW+RPW) into the ring.
    // Global src is per-lane (lane*16B); LDS dest is wave-uniform (HW adds lane*16).
    auto stage = [&](int bt) {
        const float* gsrc = xrow + (size_t)bt * (BATCH * H_DIM)
                                 + (size_t)(wv * RPW) * H_DIM + lane * 4;
        l_f* lds = (l_f*)&X[bt % RING][wv * RPW][0];
#pragma unroll
        for (int r = 0; r < RPW; ++r)
            __builtin_amdgcn_global_load_lds((g_f*)(gsrc + r * H_DIM),
                                             lds + r * H_DIM, 16, 0, 0);
    };

    stage(0);
    stage(1);

#pragma unroll 1
    for (int j = 0; j < NBATCH; ++j) {
        if (j + DEPTH < NBATCH) stage(j + DEPTH);   // 10 glds, stay in flight

        // Precise counted waits. Per wave per batch: 10 glds + 10 packed stores.
        // newer-than-glds(j): j=0: glds(1,2)=20; j=1: st(0)+glds(2,3)=30;
        // steady j in [2, NBATCH-3]: st(j-2)+glds(j+1)+st(j-1)+glds(j+2)=40;
        // j=NBATCH-2: st+glds+st=30; j=NBATCH-1: st+st=20.  (audited, in-order vmcnt)
        if      (j == 0)             { asm volatile("s_waitcnt vmcnt(20)" ::: "memory"); }
        else if (j == 1)             { asm volatile("s_waitcnt vmcnt(30)" ::: "memory"); }
        else if (j <  NBATCH - DEPTH){ asm volatile("s_waitcnt vmcnt(40)" ::: "memory"); }
        else if (j == NBATCH - 2)    { asm volatile("s_waitcnt vmcnt(30)" ::: "memory"); }
        else                         { asm volatile("s_waitcnt vmcnt(20)" ::: "memory"); }
        __builtin_amdgcn_sched_barrier(0);
        __builtin_amdgcn_s_barrier();   // all waves' slices of batch j are in LDS

        const float(*Xj)[H_DIM] = X[j % RING];
#pragma unroll 1
        for (int g = 0; g < BATCH / 4; ++g) {
#pragma unroll
            for (int r = 0; r < 4; ++r) {
                float xt = Xj[4 * g + r][tid];   // LDS read, conflict-free
                float vd = v * d;                // round(v*d)
                float vg = z ? 0.0f : vd;        // *(1-z): exact
                v = vg + xt;                     // round(+x_t)
                z = (v > 0.5f);                  // == (v - 0.5 > 0)
                S[wv][r][lane] = z ? 1.0f : 0.0f;   // stride-4B write: conflict-free
            }
            // wave-local transpose readback (DS pipe is in-order per wave: the
            // b128 read issues after the 4 writes; lgkmcnt before the store is
            // compiler-inserted). 16 consecutive lanes read 256B sequential: no
            // bank conflicts. One 1KB dwordx4 nt store per wave per 4 rows.
            v4f pk = *(const v4f*)&S[wv][tsub][hofs];
            __builtin_nontemporal_store(pk,
                (v4f*)(obase + (size_t)(j * BATCH + 4 * g + tsub) * H_DIM
                             + (wv << 6) + hofs));
        }

        __builtin_amdgcn_s_barrier();   // close ring-slot reuse race (RING=DEPTH+1)
    }
}

extern "C" void kernel_launch(void* const* d_in, const int* in_sizes, int n_in,
                              void* d_out, int out_size, void* d_ws, size_t ws_size,
                              hipStream_t stream)
{
    const float* x  = (const float*)d_in[0];         // [B,T,H] f32
    const float* dl = (const float*)d_in[1];         // [H] f32
    float*       o  = (float*)d_out;                 // [B,T,H] f32 spikes

    const int B = in_sizes[0] / (T_LEN * H_DIM);     // 256
    lif_fwd<<<B, 256, 0, stream>>>(x, dl, o);
}